// Round 1
// baseline (418.320 us; speedup 1.0000x reference)
//
#include <hip/hip_runtime.h>
#include <math.h>

// B=8, N1=64, N2=4096, C=768, H=12, hd=64, scale=1/8.
// Pipeline (all big GEMMs bf16-MFMA, softmax math fp32):
//   cast x,Wqkv,Wproj,y -> bf16
//   Qbf  [512,768]    = xbf @ Wq^T        (MFMA gemm, bf16 out)
//   KVbf [32768,1536] = ybf @ Wkv^T       (MFMA gemm, bf16 out)
//   pass1 (MFMA S=QK^T) -> per-chunk (max,sumexp); combine -> (gmax, 1/gsum)
//   pass2 (MFMA S) -> Ebf[key, h*64+j] = softmax_p * V   (bf16)
//   out  [32768,768]  = Ebf @ Wproj^T + b (MFMA gemm, f32 out)

typedef __attribute__((ext_vector_type(8))) short short8;
typedef __attribute__((ext_vector_type(4))) float f32x4;

__device__ __forceinline__ ushort f2bf(float x) {
  unsigned u = __float_as_uint(x);
  u += 0x7fffu + ((u >> 16) & 1u);          // round-to-nearest-even
  return (ushort)(u >> 16);
}
__device__ __forceinline__ float bf2f(ushort h) {
  return __uint_as_float((unsigned)h << 16);
}

// async global->LDS, 16B per lane; LDS dest = wave-uniform base + lane*16
__device__ __forceinline__ void gl_lds16(const ushort* g, ushort* l) {
  __builtin_amdgcn_global_load_lds(
      (__attribute__((address_space(1))) void*)g,
      (__attribute__((address_space(3))) void*)l, 16, 0, 0);
}

// ---------------- fp32 -> bf16 cast, 8 elems/thread ----------------
__global__ __launch_bounds__(256) void cast_f32_bf16(
    const float* __restrict__ src, ushort* __restrict__ dst, int n) {
  int i = (blockIdx.x * 256 + threadIdx.x) * 8;
  if (i >= n) return;
  float4 a = *(const float4*)(src + i);
  float4 b = *(const float4*)(src + i + 4);
  ushort o[8] = {f2bf(a.x), f2bf(a.y), f2bf(a.z), f2bf(a.w),
                 f2bf(b.x), f2bf(b.y), f2bf(b.z), f2bf(b.w)};
  *(uint4*)(dst + i) = *(const uint4*)o;
}

// ---------------- bf16 MFMA GEMM: C[M,N] = A[M,K] @ B[N,K]^T ----------------
// 128x128 tile, BK=32, global_load_lds staging (double-buffered, 1 barrier/iter),
// granule swizzle sigma_r(c) = (c + (r>>1)) & 3 -> 2-way-max ds_read banks.
// XCD swizzle (swz=1): 16-row-tile bands per XCD sweeping all col tiles.
template <typename CT>
__global__ __launch_bounds__(256) void gemm_bf16_nt(
    const ushort* __restrict__ A, int lda,
    const ushort* __restrict__ B, int ldb,
    CT* __restrict__ C, int ldc, int K,
    const float* __restrict__ bias,
    int m_tiles, int n_tiles, int swz)
{
  __shared__ __align__(16) ushort As[2][4096];
  __shared__ __align__(16) ushort Bs[2][4096];
  const int tid = threadIdx.x;
  int rt, ct;
  {
    int id = blockIdx.x;
    if (swz) {
      int xcd = id & 7, local = id >> 3;
      int per = n_tiles * 16;
      int grp = local / per, s = local % per;
      rt = xcd * (m_tiles >> 3) + grp * 16 + (s & 15);
      ct = s >> 4;
    } else { rt = id % m_tiles; ct = id / m_tiles; }
  }
  const int m0 = rt * 128, n0 = ct * 128;

  const int w = tid >> 6, lane = tid & 63;
  const int lm = lane & 15, quad = lane >> 4;
  const int wm = (w & 1) * 64, wn = (w >> 1) * 64;

  // staging geometry: granule G = row*4 + p; lane covers G0 = w*64+lane, G1 = G0+256
  const int G0 = w * 64 + lane, G1 = G0 + 256;
  const int r0 = G0 >> 2, c0 = ((G0 & 3) - (r0 >> 1)) & 3;
  const int r1 = G1 >> 2, c1 = ((G1 & 3) - (r1 >> 1)) & 3;
  const ushort* Ag0 = A + (size_t)(m0 + r0) * lda + c0 * 8;
  const ushort* Ag1 = A + (size_t)(m0 + r1) * lda + c1 * 8;
  const ushort* Bg0 = B + (size_t)(n0 + r0) * ldb + c0 * 8;
  const ushort* Bg1 = B + (size_t)(n0 + r1) * ldb + c1 * 8;
  const int lds0 = w * 512, lds1 = w * 512 + 2048;   // ushort offsets

  f32x4 acc[4][4];
#pragma unroll
  for (int i = 0; i < 4; ++i)
#pragma unroll
    for (int j = 0; j < 4; ++j) acc[i][j] = (f32x4)(0.f);

  const int nk = K >> 5;
  // prologue loads -> buf0
  gl_lds16(Ag0, &As[0][lds0]); gl_lds16(Ag1, &As[0][lds1]);
  gl_lds16(Bg0, &Bs[0][lds0]); gl_lds16(Bg1, &Bs[0][lds1]);

  int cur = 0;
  for (int kk = 0; kk < nk; ++kk) {
    __syncthreads();   // drains vmcnt: buf[cur] ready; prev reads of buf[cur^1] done
    if (kk + 1 < nk) {
      const int k0 = (kk + 1) << 5;
      gl_lds16(Ag0 + k0, &As[cur ^ 1][lds0]); gl_lds16(Ag1 + k0, &As[cur ^ 1][lds1]);
      gl_lds16(Bg0 + k0, &Bs[cur ^ 1][lds0]); gl_lds16(Bg1 + k0, &Bs[cur ^ 1][lds1]);
    }
    const ushort* Ab = &As[cur][0];
    const ushort* Bb = &Bs[cur][0];
    short8 af[4], bf8[4];
#pragma unroll
    for (int i = 0; i < 4; ++i) {
      const int Ra = wm + i * 16 + lm;
      af[i] = *(const short8*)(const void*)(Ab + Ra * 32 + ((quad + (Ra >> 1)) & 3) * 8);
      const int Rb = wn + i * 16 + lm;
      bf8[i] = *(const short8*)(const void*)(Bb + Rb * 32 + ((quad + (Rb >> 1)) & 3) * 8);
    }
#pragma unroll
    for (int i = 0; i < 4; ++i)
#pragma unroll
      for (int j = 0; j < 4; ++j)
        acc[i][j] = __builtin_amdgcn_mfma_f32_16x16x32_bf16(af[i], bf8[j], acc[i][j], 0, 0, 0);
    cur ^= 1;
  }
  __syncthreads();   // LDS free for epilogue scratch

  if constexpr (sizeof(CT) == 2) {
    // bf16 out: LDS-bounce to coalesced dwordx4 stores. 4KB scratch/wave in Bs.
    ushort* eb = ((ushort*)&Bs[0][0]) + w * 2048;
#pragma unroll
    for (int i = 0; i < 4; ++i) {
      ushort* ebc = eb + (i & 1) * 1024;    // ping-pong between chunks
#pragma unroll
      for (int j = 0; j < 4; ++j)
#pragma unroll
        for (int r = 0; r < 4; ++r) {
          const int R = quad * 4 + r;
          const int gt = j * 2 + (lm >> 3);
          const int gs = (gt + R) & 7;      // granule swizzle
          ebc[R * 64 + gs * 8 + (lm & 7)] = f2bf(acc[i][j][r]);
        }
#pragma unroll
      for (int p = 0; p < 2; ++p) {
        const int R2 = (lane >> 3) + p * 8;
        const int g = lane & 7;
        const int gt2 = (g - R2) & 7;
        uint4 v = *(const uint4*)(const void*)(ebc + R2 * 64 + g * 8);
        *(uint4*)(C + (size_t)(m0 + wm + i * 16 + R2) * ldc + n0 + wn + gt2 * 8) = v;
      }
    }
  } else {
    // f32 out + bias
#pragma unroll
    for (int j = 0; j < 4; ++j) {
      const int col = n0 + wn + j * 16 + lm;
      const float bb = bias ? bias[col] : 0.f;
#pragma unroll
      for (int i = 0; i < 4; ++i) {
        const int row = m0 + wm + i * 16 + quad * 4;
#pragma unroll
        for (int r = 0; r < 4; ++r)
          C[(size_t)(row + r) * ldc + col] = (CT)(acc[i][j][r] + bb);
      }
    }
  }
}

// ---------------- pass 1: MFMA S=QK^T, per-chunk (max,sumexp) ----------------
// grid (32 chunks, 12 h, 8 b), 256 threads. Wave w: keys [w*32, w*32+32).
__global__ __launch_bounds__(256) void attn_pass1(
    const ushort* __restrict__ Q,     // [512,768] bf16
    const ushort* __restrict__ KV,    // [32768,1536] bf16, K cols 0..767
    float* __restrict__ parts)        // [96][32][64][2]
{
  const int chunk = blockIdx.x, h = blockIdx.y, b = blockIdx.z;
  const int tid = threadIdx.x;
  __shared__ __align__(16) ushort Qs[64 * 72];
  __shared__ __align__(16) ushort Ks[128 * 72];
  __shared__ float sm[4][64], ss[4][64];
#pragma unroll
  for (int p = 0; p < 2; ++p) {
    const int G = tid + 256 * p, row = G >> 3, g = G & 7;
    *(uint4*)(Qs + row * 72 + g * 8) =
        *(const uint4*)(Q + (size_t)(b * 64 + row) * 768 + h * 64 + g * 8);
  }
#pragma unroll
  for (int p = 0; p < 4; ++p) {
    const int G = tid + 256 * p, row = G >> 3, g = G & 7;
    *(uint4*)(Ks + row * 72 + g * 8) =
        *(const uint4*)(KV + (size_t)(b * 4096 + chunk * 128 + row) * 1536 + h * 64 + g * 8);
  }
  __syncthreads();

  const int w = tid >> 6, lane = tid & 63;
  const int lm = lane & 15, quad = lane >> 4;
  const int wn = w * 32;

  f32x4 acc[4][2];
#pragma unroll
  for (int i = 0; i < 4; ++i) { acc[i][0] = (f32x4)(0.f); acc[i][1] = (f32x4)(0.f); }
#pragma unroll
  for (int s = 0; s < 2; ++s) {
    short8 qf[4], kf[2];
#pragma unroll
    for (int i = 0; i < 4; ++i)
      qf[i] = *(const short8*)(const void*)(Qs + (i * 16 + lm) * 72 + s * 32 + quad * 8);
#pragma unroll
    for (int jn = 0; jn < 2; ++jn)
      kf[jn] = *(const short8*)(const void*)(Ks + (wn + jn * 16 + lm) * 72 + s * 32 + quad * 8);
#pragma unroll
    for (int i = 0; i < 4; ++i)
#pragma unroll
      for (int jn = 0; jn < 2; ++jn)
        acc[i][jn] = __builtin_amdgcn_mfma_f32_16x16x32_bf16(qf[i], kf[jn], acc[i][jn], 0, 0, 0);
  }

#pragma unroll
  for (int i = 0; i < 4; ++i)
#pragma unroll
    for (int r = 0; r < 4; ++r) {
      float v0 = acc[i][0][r] * 0.125f, v1 = acc[i][1][r] * 0.125f;
      float m = fmaxf(v0, v1);
      m = fmaxf(m, __shfl_xor(m, 1)); m = fmaxf(m, __shfl_xor(m, 2));
      m = fmaxf(m, __shfl_xor(m, 4)); m = fmaxf(m, __shfl_xor(m, 8));
      float e = __expf(v0 - m) + __expf(v1 - m);
      e += __shfl_xor(e, 1); e += __shfl_xor(e, 2);
      e += __shfl_xor(e, 4); e += __shfl_xor(e, 8);
      if (lm == 0) {
        const int j = i * 16 + quad * 4 + r;
        sm[w][j] = m; ss[w][j] = e;
      }
    }
  __syncthreads();
  if (tid < 64) {
    float g = fmaxf(fmaxf(sm[0][tid], sm[1][tid]), fmaxf(sm[2][tid], sm[3][tid]));
    float s = ss[0][tid] * __expf(sm[0][tid] - g) + ss[1][tid] * __expf(sm[1][tid] - g)
            + ss[2][tid] * __expf(sm[2][tid] - g) + ss[3][tid] * __expf(sm[3][tid] - g);
    const int bh = b * 12 + h;
    float* p = parts + ((size_t)(bh * 32 + chunk) * 64 + tid) * 2;
    p[0] = g; p[1] = s;
  }
}

// ---------------- combine partials -> (gmax, 1/gsum) ----------------
__global__ void attn_combine(const float* __restrict__ parts, float* __restrict__ stats)
{
  const int bh = blockIdx.x, j = threadIdx.x;   // 96 blocks x 64 threads
  float pm[32], ps[32];
  float g = -1e30f;
#pragma unroll
  for (int c = 0; c < 32; ++c) {
    const float* p = parts + ((size_t)(bh * 32 + c) * 64 + j) * 2;
    pm[c] = p[0]; ps[c] = p[1];
    g = fmaxf(g, pm[c]);
  }
  float s = 0.f;
#pragma unroll
  for (int c = 0; c < 32; ++c) s += ps[c] * __expf(pm[c] - g);
  stats[(size_t)(bh * 64 + j) * 2]     = g;
  stats[(size_t)(bh * 64 + j) * 2 + 1] = 1.f / s;
}

// ---------------- pass 2: MFMA S, Ebf[key, h*64+j] = p * V ----------------
__global__ __launch_bounds__(256) void attn_pass2(
    const ushort* __restrict__ Q, const ushort* __restrict__ KV,
    const float* __restrict__ stats, ushort* __restrict__ E)
{
  const int chunk = blockIdx.x, h = blockIdx.y, b = blockIdx.z;
  const int tid = threadIdx.x;
  __shared__ __align__(16) ushort Qs[64 * 72];
  __shared__ __align__(16) ushort Ks[128 * 72];
  __shared__ __align__(16) ushort Vs[128 * 72];
  __shared__ float st[64][2];
#pragma unroll
  for (int p = 0; p < 2; ++p) {
    const int G = tid + 256 * p, row = G >> 3, g = G & 7;
    *(uint4*)(Qs + row * 72 + g * 8) =
        *(const uint4*)(Q + (size_t)(b * 64 + row) * 768 + h * 64 + g * 8);
  }
#pragma unroll
  for (int p = 0; p < 4; ++p) {
    const int G = tid + 256 * p, row = G >> 3, g = G & 7;
    const size_t rbase = (size_t)(b * 4096 + chunk * 128 + row) * 1536 + h * 64 + g * 8;
    *(uint4*)(Ks + row * 72 + g * 8) = *(const uint4*)(KV + rbase);
    *(uint4*)(Vs + row * 72 + g * 8) = *(const uint4*)(KV + rbase + 768);
  }
  const int bh = b * 12 + h;
  if (tid < 128) st[tid >> 1][tid & 1] = stats[(size_t)(bh * 64 + (tid >> 1)) * 2 + (tid & 1)];
  __syncthreads();

  const int w = tid >> 6, lane = tid & 63;
  const int lm = lane & 15, quad = lane >> 4;
  const int wn = w * 32;

  f32x4 acc[4][2];
#pragma unroll
  for (int i = 0; i < 4; ++i) { acc[i][0] = (f32x4)(0.f); acc[i][1] = (f32x4)(0.f); }
#pragma unroll
  for (int s = 0; s < 2; ++s) {
    short8 qf[4], kf[2];
#pragma unroll
    for (int i = 0; i < 4; ++i)
      qf[i] = *(const short8*)(const void*)(Qs + (i * 16 + lm) * 72 + s * 32 + quad * 8);
#pragma unroll
    for (int jn = 0; jn < 2; ++jn)
      kf[jn] = *(const short8*)(const void*)(Ks + (wn + jn * 16 + lm) * 72 + s * 32 + quad * 8);
#pragma unroll
    for (int i = 0; i < 4; ++i)
#pragma unroll
      for (int jn = 0; jn < 2; ++jn)
        acc[i][jn] = __builtin_amdgcn_mfma_f32_16x16x32_bf16(qf[i], kf[jn], acc[i][jn], 0, 0, 0);
  }

  ushort ev[4][2][4];
#pragma unroll
  for (int i = 0; i < 4; ++i)
#pragma unroll
    for (int jn = 0; jn < 2; ++jn)
#pragma unroll
      for (int r = 0; r < 4; ++r) {
        const float v = acc[i][jn][r] * 0.125f;
        const int j = i * 16 + quad * 4 + r;
        const float p = __expf(v - st[j][0]) * st[j][1];
        const int key = wn + jn * 16 + lm;
        ev[i][jn][r] = f2bf(p * bf2f(Vs[key * 72 + j]));
      }
  __syncthreads();                 // all frag reads of Ks done -> reuse as E staging
  ushort* Es = Ks;
#pragma unroll
  for (int i = 0; i < 4; ++i)
#pragma unroll
    for (int jn = 0; jn < 2; ++jn)
#pragma unroll
      for (int r = 0; r < 4; ++r)
        Es[(wn + jn * 16 + lm) * 72 + i * 16 + quad * 4 + r] = ev[i][jn][r];
  __syncthreads();
#pragma unroll
  for (int k = 0; k < 4; ++k) {
    const int row = tid >> 1, g = (tid & 1) * 4 + k;
    uint4 v = *(const uint4*)(const void*)(Es + row * 72 + g * 8);
    *(uint4*)(E + (size_t)(b * 4096 + chunk * 128 + row) * 768 + h * 64 + g * 8) = v;
  }
}

extern "C" void kernel_launch(void* const* d_in, const int* in_sizes, int n_in,
                              void* d_out, int out_size, void* d_ws, size_t ws_size,
                              hipStream_t stream) {
  const float* x     = (const float*)d_in[0];   // [8,64,768]
  const float* y     = (const float*)d_in[1];   // [8,4096,768]
  const float* Wqkv  = (const float*)d_in[2];   // [2304,768]
  const float* Wproj = (const float*)d_in[3];   // [768,768]
  const float* bproj = (const float*)d_in[4];   // [768]
  float* out = (float*)d_out;                   // [8,4096,768]

  // workspace layout (bytes), total 157,286,400 (< proven 157.7 MB):
  //   xbf    bf16 [512,768]    @ 0
  //   qbf    bf16 [512,768]    @ 786432
  //   wqkvbf bf16 [2304,768]   @ 1572864   (3,538,944) -- dead after KV gemm
  //     parts f32 [96,32,64,2] @ 1572864   (alias, used after)
  //     stats f32 [96,64,2]    @ 3145728   (alias)
  //   wpbf   bf16 [768,768]    @ 5111808
  //   ybf/Ebf bf16 [32768,768] @ 6291456   (Ebf aliases dead ybf)
  //   KVbf   bf16 [32768,1536] @ 56623104
  char* wsb = (char*)d_ws;
  ushort* xbf    = (ushort*)(wsb + 0);
  ushort* qbf    = (ushort*)(wsb + 786432);
  ushort* wqkvbf = (ushort*)(wsb + 1572864);
  float*  parts  = (float*)(wsb + 1572864);
  float*  stats  = (float*)(wsb + 3145728);
  ushort* wpbf   = (ushort*)(wsb + 5111808);
  ushort* ybf    = (ushort*)(wsb + 6291456);
  ushort* Ebf    = ybf;
  ushort* KVbf   = (ushort*)(wsb + 56623104);

  // casts
  cast_f32_bf16<<<(393216/8 + 255)/256, 256, 0, stream>>>(x, xbf, 393216);
  cast_f32_bf16<<<(1769472/8 + 255)/256, 256, 0, stream>>>(Wqkv, wqkvbf, 1769472);
  cast_f32_bf16<<<(589824/8 + 255)/256, 256, 0, stream>>>(Wproj, wpbf, 589824);
  cast_f32_bf16<<<(25165824/8 + 255)/256, 256, 0, stream>>>(y, ybf, 25165824);

  // Q projection: [512,768] = xbf @ Wq^T (bf16 out)
  gemm_bf16_nt<ushort><<<24, 256, 0, stream>>>(
      xbf, 768, wqkvbf, 768, qbf, 768, 768, nullptr, 4, 6, 0);
  // KV projection: [32768,1536] = ybf @ Wkv^T (bf16 out)
  gemm_bf16_nt<ushort><<<3072, 256, 0, stream>>>(
      ybf, 768, wqkvbf + (size_t)768 * 768, 768, KVbf, 1536, 768, nullptr, 256, 12, 1);

  // softmax stats (two-pass flash style, MFMA S)
  attn_pass1<<<dim3(32, 12, 8), 256, 0, stream>>>(qbf, KVbf, parts);
  attn_combine<<<96, 64, 0, stream>>>(parts, stats);
  attn_pass2<<<dim3(32, 12, 8), 256, 0, stream>>>(qbf, KVbf, stats, Ebf);

  // out = Ebf @ Wproj^T + b (f32 out)
  gemm_bf16_nt<float><<<1536, 256, 0, stream>>>(
      Ebf, 768, wpbf, 768, out, 768, 768, bproj, 256, 6, 1);
}

// Round 2
// 405.400 us; speedup vs baseline: 1.0319x; 1.0319x over previous
//
#include <hip/hip_runtime.h>
#include <math.h>

// B=8, N1=64, N2=4096, C=768, H=12, hd=64, scale=1/8.
// Pipeline (all big GEMMs bf16-MFMA, softmax math fp32):
//   cast_all: x,Wqkv,Wproj,y -> bf16 (one kernel)
//   qkv_gemm: KV [32768,1536] = ybf @ Wkv^T  (3072 blocks) + Q [512,768] = xbf @ Wq^T (24 blocks)
//   pass1 (MFMA S=QK^T) -> per-chunk (max,sumexp) partials
//   pass2 (MFMA S) -> inline combine of partials -> Ebf[key, h*64+j] = softmax_p * V
//   out_gemm [32768,768] = Ebf @ Wproj^T + b (f32 out)
// GEMM core: 128x128 tile, BK=32, 3-buffer global_load_lds pipeline with raw
// s_barrier + per-wave trailing s_waitcnt vmcnt(4) (counted, never drains in
// steady state; waited-on loads are ~2 iterations old).

typedef __attribute__((ext_vector_type(8))) short short8;
typedef __attribute__((ext_vector_type(4))) float f32x4;

__device__ __forceinline__ ushort f2bf(float x) {
  unsigned u = __float_as_uint(x);
  u += 0x7fffu + ((u >> 16) & 1u);          // round-to-nearest-even
  return (ushort)(u >> 16);
}
__device__ __forceinline__ float bf2f(ushort h) {
  return __uint_as_float((unsigned)h << 16);
}

// async global->LDS, 16B per lane; LDS dest = wave-uniform base + lane*16
__device__ __forceinline__ void gl_lds16(const ushort* g, ushort* l) {
  __builtin_amdgcn_global_load_lds(
      (__attribute__((address_space(1))) void*)g,
      (__attribute__((address_space(3))) void*)l, 16, 0, 0);
}

// ---------------- fused fp32 -> bf16 casts, 8 elems/thread ----------------
// element ranges (all multiples of 8): x 393216 | Wqkv 1769472 | Wproj 589824 | y 25165824
__global__ __launch_bounds__(256) void cast_all(
    const float* __restrict__ x, ushort* __restrict__ xb,
    const float* __restrict__ w1, ushort* __restrict__ w1b,
    const float* __restrict__ w2, ushort* __restrict__ w2b,
    const float* __restrict__ y, ushort* __restrict__ yb) {
  long i = (long)(blockIdx.x * 256 + threadIdx.x) * 8;
  if (i >= 27918336L) return;
  const float* s; ushort* d; long off;
  if (i < 393216L)        { s = x;  d = xb;  off = i; }
  else if (i < 2162688L)  { s = w1; d = w1b; off = i - 393216L; }
  else if (i < 2752512L)  { s = w2; d = w2b; off = i - 2162688L; }
  else                    { s = y;  d = yb;  off = i - 2752512L; }
  float4 a = *(const float4*)(s + off);
  float4 b = *(const float4*)(s + off + 4);
  ushort o[8] = {f2bf(a.x), f2bf(a.y), f2bf(a.z), f2bf(a.w),
                 f2bf(b.x), f2bf(b.y), f2bf(b.z), f2bf(b.w)};
  *(uint4*)(d + off) = *(const uint4*)o;
}

// ---------------- bf16 MFMA GEMM body: C[M,N] tile = A[M,K] @ B[N,K]^T ----------------
// 128x128 tile, BK=32, 3-buffer pipeline (prefetch distance 2).
// granule swizzle sigma_r(c) = (c + (r>>1)) & 3 -> 2-way-max ds_read banks.
// Safety argument for the raw-barrier pipeline:
//  - each wave's trailing vmcnt(4) (end of iter kk) waits its OWN L(kk+1) slice
//    (issued early in iter kk-1, ~2 iters old) while leaving L(kk+2)'s 4 loads
//    in flight; so at the top barrier of iter kk+1 ALL waves' L(kk+1) landed.
//  - staging L(kk+2) happens after the top barrier of iter kk, by which point
//    every wave has finished its reads of tile kk-1 (same buffer): ds_reads
//    complete (lgkmcnt) before the MFMAs that consume them, which precede the
//    barrier in program order.
template <typename CT>
__device__ __forceinline__ void gemm_body(
    const ushort* __restrict__ A, int lda,
    const ushort* __restrict__ B, int ldb,
    CT* __restrict__ C, int ldc, int K,
    const float* __restrict__ bias, int rt, int ct)
{
  __shared__ __align__(16) ushort As[3][4096];
  __shared__ __align__(16) ushort Bs[3][4096];
  const int tid = threadIdx.x;
  const int m0 = rt * 128, n0 = ct * 128;

  const int w = tid >> 6, lane = tid & 63;
  const int lm = lane & 15, quad = lane >> 4;
  const int wm = (w & 1) * 64, wn = (w >> 1) * 64;

  // staging geometry: granule G = row*4 + p; lane covers G0 = w*64+lane, G1 = G0+256
  const int G0 = w * 64 + lane, G1 = G0 + 256;
  const int r0 = G0 >> 2, c0 = ((G0 & 3) - (r0 >> 1)) & 3;
  const int r1 = G1 >> 2, c1 = ((G1 & 3) - (r1 >> 1)) & 3;
  const ushort* Ag0 = A + (size_t)(m0 + r0) * lda + c0 * 8;
  const ushort* Ag1 = A + (size_t)(m0 + r1) * lda + c1 * 8;
  const ushort* Bg0 = B + (size_t)(n0 + r0) * ldb + c0 * 8;
  const ushort* Bg1 = B + (size_t)(n0 + r1) * ldb + c1 * 8;
  const int lds0 = w * 512, lds1 = w * 512 + 2048;   // ushort offsets

  f32x4 acc[4][4];
#pragma unroll
  for (int i = 0; i < 4; ++i)
#pragma unroll
    for (int j = 0; j < 4; ++j) acc[i][j] = (f32x4)(0.f);

  const int nk = K >> 5;                  // = 24 here (nk >= 3 assumed)
  // prologue: stage tiles 0 and 1
  gl_lds16(Ag0, &As[0][lds0]); gl_lds16(Ag1, &As[0][lds1]);
  gl_lds16(Bg0, &Bs[0][lds0]); gl_lds16(Bg1, &Bs[0][lds1]);
  gl_lds16(Ag0 + 32, &As[1][lds0]); gl_lds16(Ag1 + 32, &As[1][lds1]);
  gl_lds16(Bg0 + 32, &Bs[1][lds0]); gl_lds16(Bg1 + 32, &Bs[1][lds1]);
  asm volatile("s_waitcnt vmcnt(4)" ::: "memory");   // own L0 landed; L1 in flight

  for (int kk = 0; kk < nk; ++kk) {
    __builtin_amdgcn_s_barrier();        // raw: no vmcnt(0) drain
    __builtin_amdgcn_sched_barrier(0);
    if (kk + 2 < nk) {                   // stage L(kk+2) into buffer of tile kk-1
      const int k0 = (kk + 2) << 5;
      ushort* Ad = &As[(kk + 2) % 3][0];
      ushort* Bd = &Bs[(kk + 2) % 3][0];
      gl_lds16(Ag0 + k0, Ad + lds0); gl_lds16(Ag1 + k0, Ad + lds1);
      gl_lds16(Bg0 + k0, Bd + lds0); gl_lds16(Bg1 + k0, Bd + lds1);
    }
    const ushort* Ab = &As[kk % 3][0];
    const ushort* Bb = &Bs[kk % 3][0];
    short8 af[4], bf8[4];
#pragma unroll
    for (int i = 0; i < 4; ++i) {
      const int Ra = wm + i * 16 + lm;
      af[i] = *(const short8*)(const void*)(Ab + Ra * 32 + ((quad + (Ra >> 1)) & 3) * 8);
      const int Rb = wn + i * 16 + lm;
      bf8[i] = *(const short8*)(const void*)(Bb + Rb * 32 + ((quad + (Rb >> 1)) & 3) * 8);
    }
#pragma unroll
    for (int i = 0; i < 4; ++i)
#pragma unroll
      for (int j = 0; j < 4; ++j)
        acc[i][j] = __builtin_amdgcn_mfma_f32_16x16x32_bf16(af[i], bf8[j], acc[i][j], 0, 0, 0);
    // trailing wait: own L(kk+1) landed before next iter's barrier releases readers
    if (kk < nk - 2)       asm volatile("s_waitcnt vmcnt(4)" ::: "memory");
    else if (kk == nk - 2) asm volatile("s_waitcnt vmcnt(0)" ::: "memory");
  }
  __syncthreads();   // LDS free for epilogue scratch; all loads drained

  if constexpr (sizeof(CT) == 2) {
    // bf16 out: LDS-bounce to coalesced dwordx4 stores. 4KB scratch/wave in Bs.
    ushort* eb = ((ushort*)&Bs[0][0]) + w * 2048;
#pragma unroll
    for (int i = 0; i < 4; ++i) {
      ushort* ebc = eb + (i & 1) * 1024;    // ping-pong between chunks
#pragma unroll
      for (int j = 0; j < 4; ++j)
#pragma unroll
        for (int r = 0; r < 4; ++r) {
          const int R = quad * 4 + r;
          const int gt = j * 2 + (lm >> 3);
          const int gs = (gt + R) & 7;      // granule swizzle
          ebc[R * 64 + gs * 8 + (lm & 7)] = f2bf(acc[i][j][r]);
        }
#pragma unroll
      for (int p = 0; p < 2; ++p) {
        const int R2 = (lane >> 3) + p * 8;
        const int g = lane & 7;
        const int gt2 = (g - R2) & 7;
        uint4 v = *(const uint4*)(const void*)(ebc + R2 * 64 + g * 8);
        *(uint4*)(C + (size_t)(m0 + wm + i * 16 + R2) * ldc + n0 + wn + gt2 * 8) = v;
      }
    }
  } else {
    // f32 out + bias
#pragma unroll
    for (int j = 0; j < 4; ++j) {
      const int col = n0 + wn + j * 16 + lm;
      const float bb = bias ? bias[col] : 0.f;
#pragma unroll
      for (int i = 0; i < 4; ++i) {
        const int row = m0 + wm + i * 16 + quad * 4;
#pragma unroll
        for (int r = 0; r < 4; ++r)
          C[(size_t)(row + r) * ldc + col] = (CT)(acc[i][j][r] + bb);
      }
    }
  }
}

// ---------------- fused QKV projections: KV (3072 blocks, XCD-swz) + Q (24 blocks) ----------------
__global__ __launch_bounds__(256) void qkv_gemm(
    const ushort* __restrict__ xbf, const ushort* __restrict__ ybf,
    const ushort* __restrict__ wqkv, ushort* __restrict__ qbf,
    ushort* __restrict__ kvbf)
{
  const int id = blockIdx.x;
  const ushort *A, *B; ushort* C; int ldc, rt, ct;
  if (id < 3072) {
    // KV: m_tiles=256, n_tiles=12, XCD swizzle (16-row-tile bands per XCD)
    const int xcd = id & 7, local = id >> 3;
    const int per = 12 * 16;
    const int grp = local / per, s = local % per;
    rt = xcd * 32 + grp * 16 + (s & 15);
    ct = s >> 4;
    A = ybf; B = wqkv + (size_t)768 * 768; C = kvbf; ldc = 1536;
  } else {
    // Q: m_tiles=4, n_tiles=6
    const int id2 = id - 3072;
    rt = id2 & 3; ct = id2 >> 2;
    A = xbf; B = wqkv; C = qbf; ldc = 768;
  }
  gemm_body<ushort>(A, 768, B, 768, C, ldc, 768, nullptr, rt, ct);
}

// ---------------- out = Ebf @ Wproj^T + b (f32 out, 1536 blocks, XCD-swz) ----------------
__global__ __launch_bounds__(256) void out_gemm(
    const ushort* __restrict__ Ebf, const ushort* __restrict__ wpbf,
    const float* __restrict__ bias, float* __restrict__ out)
{
  const int id = blockIdx.x;            // m_tiles=256, n_tiles=6
  const int xcd = id & 7, local = id >> 3;
  const int per = 6 * 16;
  const int grp = local / per, s = local % per;
  const int rt = xcd * 32 + grp * 16 + (s & 15);
  const int ct = s >> 4;
  gemm_body<float>(Ebf, 768, wpbf, 768, out, 768, 768, bias, rt, ct);
}

// ---------------- pass 1: MFMA S=QK^T, per-chunk (max,sumexp) ----------------
// grid (32 chunks, 12 h, 8 b), 256 threads. Wave w: keys [w*32, w*32+32).
__global__ __launch_bounds__(256) void attn_pass1(
    const ushort* __restrict__ Q,     // [512,768] bf16
    const ushort* __restrict__ KV,    // [32768,1536] bf16, K cols 0..767
    float* __restrict__ parts)        // [96][32][64][2]
{
  const int chunk = blockIdx.x, h = blockIdx.y, b = blockIdx.z;
  const int tid = threadIdx.x;
  __shared__ __align__(16) ushort Qs[64 * 72];
  __shared__ __align__(16) ushort Ks[128 * 72];
  __shared__ float sm[4][64], ss[4][64];
#pragma unroll
  for (int p = 0; p < 2; ++p) {
    const int G = tid + 256 * p, row = G >> 3, g = G & 7;
    *(uint4*)(Qs + row * 72 + g * 8) =
        *(const uint4*)(Q + (size_t)(b * 64 + row) * 768 + h * 64 + g * 8);
  }
#pragma unroll
  for (int p = 0; p < 4; ++p) {
    const int G = tid + 256 * p, row = G >> 3, g = G & 7;
    *(uint4*)(Ks + row * 72 + g * 8) =
        *(const uint4*)(KV + (size_t)(b * 4096 + chunk * 128 + row) * 1536 + h * 64 + g * 8);
  }
  __syncthreads();

  const int w = tid >> 6, lane = tid & 63;
  const int lm = lane & 15, quad = lane >> 4;
  const int wn = w * 32;

  f32x4 acc[4][2];
#pragma unroll
  for (int i = 0; i < 4; ++i) { acc[i][0] = (f32x4)(0.f); acc[i][1] = (f32x4)(0.f); }
#pragma unroll
  for (int s = 0; s < 2; ++s) {
    short8 qf[4], kf[2];
#pragma unroll
    for (int i = 0; i < 4; ++i)
      qf[i] = *(const short8*)(const void*)(Qs + (i * 16 + lm) * 72 + s * 32 + quad * 8);
#pragma unroll
    for (int jn = 0; jn < 2; ++jn)
      kf[jn] = *(const short8*)(const void*)(Ks + (wn + jn * 16 + lm) * 72 + s * 32 + quad * 8);
#pragma unroll
    for (int i = 0; i < 4; ++i)
#pragma unroll
      for (int jn = 0; jn < 2; ++jn)
        acc[i][jn] = __builtin_amdgcn_mfma_f32_16x16x32_bf16(qf[i], kf[jn], acc[i][jn], 0, 0, 0);
  }

#pragma unroll
  for (int i = 0; i < 4; ++i)
#pragma unroll
    for (int r = 0; r < 4; ++r) {
      float v0 = acc[i][0][r] * 0.125f, v1 = acc[i][1][r] * 0.125f;
      float m = fmaxf(v0, v1);
      m = fmaxf(m, __shfl_xor(m, 1)); m = fmaxf(m, __shfl_xor(m, 2));
      m = fmaxf(m, __shfl_xor(m, 4)); m = fmaxf(m, __shfl_xor(m, 8));
      float e = __expf(v0 - m) + __expf(v1 - m);
      e += __shfl_xor(e, 1); e += __shfl_xor(e, 2);
      e += __shfl_xor(e, 4); e += __shfl_xor(e, 8);
      if (lm == 0) {
        const int j = i * 16 + quad * 4 + r;
        sm[w][j] = m; ss[w][j] = e;
      }
    }
  __syncthreads();
  if (tid < 64) {
    float g = fmaxf(fmaxf(sm[0][tid], sm[1][tid]), fmaxf(sm[2][tid], sm[3][tid]));
    float s = ss[0][tid] * __expf(sm[0][tid] - g) + ss[1][tid] * __expf(sm[1][tid] - g)
            + ss[2][tid] * __expf(sm[2][tid] - g) + ss[3][tid] * __expf(sm[3][tid] - g);
    const int bh = b * 12 + h;
    float* p = parts + ((size_t)(bh * 32 + chunk) * 64 + tid) * 2;
    p[0] = g; p[1] = s;
  }
}

// ---------------- pass 2: inline combine + MFMA S, Ebf[key, h*64+j] = p * V ----------------
__global__ __launch_bounds__(256) void attn_pass2(
    const ushort* __restrict__ Q, const ushort* __restrict__ KV,
    const float* __restrict__ parts, ushort* __restrict__ E)
{
  const int chunk = blockIdx.x, h = blockIdx.y, b = blockIdx.z;
  const int tid = threadIdx.x;
  __shared__ __align__(16) ushort Qs[64 * 72];
  __shared__ __align__(16) ushort Ks[128 * 72];
  __shared__ __align__(16) ushort Vs[128 * 72];
  __shared__ float st[64][2];
#pragma unroll
  for (int p = 0; p < 2; ++p) {
    const int G = tid + 256 * p, row = G >> 3, g = G & 7;
    *(uint4*)(Qs + row * 72 + g * 8) =
        *(const uint4*)(Q + (size_t)(b * 64 + row) * 768 + h * 64 + g * 8);
  }
#pragma unroll
  for (int p = 0; p < 4; ++p) {
    const int G = tid + 256 * p, row = G >> 3, g = G & 7;
    const size_t rbase = (size_t)(b * 4096 + chunk * 128 + row) * 1536 + h * 64 + g * 8;
    *(uint4*)(Ks + row * 72 + g * 8) = *(const uint4*)(KV + rbase);
    *(uint4*)(Vs + row * 72 + g * 8) = *(const uint4*)(KV + rbase + 768);
  }
  // inline combine: 4 threads per query row, 8 chunks each (parts is L2/L3-resident)
  {
    const int bh = b * 12 + h;
    const int tq = tid >> 2, tc = tid & 3;
    float pm[8], ps[8];
    float gm = -1e30f;
#pragma unroll
    for (int c = 0; c < 8; ++c) {
      const float* p = parts + ((size_t)(bh * 32 + tc * 8 + c) * 64 + tq) * 2;
      pm[c] = p[0]; ps[c] = p[1];
      gm = fmaxf(gm, pm[c]);
    }
    gm = fmaxf(gm, __shfl_xor(gm, 1));
    gm = fmaxf(gm, __shfl_xor(gm, 2));
    float s = 0.f;
#pragma unroll
    for (int c = 0; c < 8; ++c) s += ps[c] * __expf(pm[c] - gm);
    s += __shfl_xor(s, 1);
    s += __shfl_xor(s, 2);
    if (tc == 0) { st[tq][0] = gm; st[tq][1] = 1.f / s; }
  }
  __syncthreads();

  const int w = tid >> 6, lane = tid & 63;
  const int lm = lane & 15, quad = lane >> 4;
  const int wn = w * 32;

  f32x4 acc[4][2];
#pragma unroll
  for (int i = 0; i < 4; ++i) { acc[i][0] = (f32x4)(0.f); acc[i][1] = (f32x4)(0.f); }
#pragma unroll
  for (int s = 0; s < 2; ++s) {
    short8 qf[4], kf[2];
#pragma unroll
    for (int i = 0; i < 4; ++i)
      qf[i] = *(const short8*)(const void*)(Qs + (i * 16 + lm) * 72 + s * 32 + quad * 8);
#pragma unroll
    for (int jn = 0; jn < 2; ++jn)
      kf[jn] = *(const short8*)(const void*)(Ks + (wn + jn * 16 + lm) * 72 + s * 32 + quad * 8);
#pragma unroll
    for (int i = 0; i < 4; ++i)
#pragma unroll
      for (int jn = 0; jn < 2; ++jn)
        acc[i][jn] = __builtin_amdgcn_mfma_f32_16x16x32_bf16(qf[i], kf[jn], acc[i][jn], 0, 0, 0);
  }

  ushort ev[4][2][4];
#pragma unroll
  for (int i = 0; i < 4; ++i)
#pragma unroll
    for (int jn = 0; jn < 2; ++jn)
#pragma unroll
      for (int r = 0; r < 4; ++r) {
        const float v = acc[i][jn][r] * 0.125f;
        const int j = i * 16 + quad * 4 + r;
        const float p = __expf(v - st[j][0]) * st[j][1];
        const int key = wn + jn * 16 + lm;
        ev[i][jn][r] = f2bf(p * bf2f(Vs[key * 72 + j]));
      }
  __syncthreads();                 // all frag reads of Ks done -> reuse as E staging
  ushort* Es = Ks;
#pragma unroll
  for (int i = 0; i < 4; ++i)
#pragma unroll
    for (int jn = 0; jn < 2; ++jn)
#pragma unroll
      for (int r = 0; r < 4; ++r)
        Es[(wn + jn * 16 + lm) * 72 + i * 16 + quad * 4 + r] = ev[i][jn][r];
  __syncthreads();
#pragma unroll
  for (int k = 0; k < 4; ++k) {
    const int row = tid >> 1, g = (tid & 1) * 4 + k;
    uint4 v = *(const uint4*)(const void*)(Es + row * 72 + g * 8);
    *(uint4*)(E + (size_t)(b * 4096 + chunk * 128 + row) * 768 + h * 64 + g * 8) = v;
  }
}

extern "C" void kernel_launch(void* const* d_in, const int* in_sizes, int n_in,
                              void* d_out, int out_size, void* d_ws, size_t ws_size,
                              hipStream_t stream) {
  const float* x     = (const float*)d_in[0];   // [8,64,768]
  const float* y     = (const float*)d_in[1];   // [8,4096,768]
  const float* Wqkv  = (const float*)d_in[2];   // [2304,768]
  const float* Wproj = (const float*)d_in[3];   // [768,768]
  const float* bproj = (const float*)d_in[4];   // [768]
  float* out = (float*)d_out;                   // [8,4096,768]

  // workspace layout (bytes), total 157,286,400:
  //   xbf    bf16 [512,768]    @ 0
  //   qbf    bf16 [512,768]    @ 786432
  //   wqkvbf bf16 [2304,768]   @ 1572864   (dead after qkv_gemm)
  //     parts f32 [96,32,64,2] @ 1572864   (alias, used after)
  //   wpbf   bf16 [768,768]    @ 5111808
  //   ybf/Ebf bf16 [32768,768] @ 6291456   (Ebf aliases dead ybf)
  //   KVbf   bf16 [32768,1536] @ 56623104
  char* wsb = (char*)d_ws;
  ushort* xbf    = (ushort*)(wsb + 0);
  ushort* qbf    = (ushort*)(wsb + 786432);
  ushort* wqkvbf = (ushort*)(wsb + 1572864);
  float*  parts  = (float*)(wsb + 1572864);
  ushort* wpbf   = (ushort*)(wsb + 5111808);
  ushort* ybf    = (ushort*)(wsb + 6291456);
  ushort* Ebf    = ybf;
  ushort* KVbf   = (ushort*)(wsb + 56623104);

  // all casts in one launch: 27,918,336 elems / 8 per thread / 256 per block
  cast_all<<<13632, 256, 0, stream>>>(x, xbf, Wqkv, wqkvbf, Wproj, wpbf, y, ybf);

  // KV projection (3072 blocks) + Q projection (24 blocks) in one launch
  qkv_gemm<<<3096, 256, 0, stream>>>(xbf, ybf, wqkvbf, qbf, KVbf);

  // softmax stats (two-pass flash style, MFMA S); combine folded into pass2
  attn_pass1<<<dim3(32, 12, 8), 256, 0, stream>>>(qbf, KVbf, parts);
  attn_pass2<<<dim3(32, 12, 8), 256, 0, stream>>>(qbf, KVbf, parts, Ebf);

  // out = Ebf @ Wproj^T + b (f32 out)
  out_gemm<<<1536, 256, 0, stream>>>(Ebf, wpbf, bproj, out);
}